// Round 3
// baseline (546.025 us; speedup 1.0000x reference)
//
#include <hip/hip_runtime.h>
#include <math.h>

#define CDIM 256
#define HW 3136
#define HID 1024

typedef __attribute__((ext_vector_type(4))) float f32x4;
typedef __attribute__((ext_vector_type(8))) short bf16x8;
typedef __attribute__((ext_vector_type(4))) short bf16x4;

__device__ __forceinline__ unsigned short f2bf(float f){
  unsigned int u = __float_as_uint(f);
  u += 0x7FFFu + ((u >> 16) & 1u);
  return (unsigned short)(u >> 16);
}

__device__ __forceinline__ void load_lds16(const void* g, void* l){
  __builtin_amdgcn_global_load_lds(
      (const __attribute__((address_space(1))) unsigned int*)g,
      (__attribute__((address_space(3))) unsigned int*)l, 16, 0, 0);
}

// ---------------- prep: w1t[f][c] = w1[c][f]; w2t[c][f] = w2[f][c]  (bf16)
__global__ __launch_bounds__(256) void prep_kernel(
    const float* __restrict__ w1, const float* __restrict__ w2,
    unsigned short* __restrict__ w1t, unsigned short* __restrict__ w2t){
  __shared__ unsigned short sh[64][70];
  int blk = blockIdx.x;
  const float* src; unsigned short* dst; int M, N, tm, tn;
  if (blk < 64){ src = w1; dst = w1t; M = 256;  N = 1024; tm = blk >> 4; tn = blk & 15; }
  else { blk -= 64; src = w2; dst = w2t; M = 1024; N = 256;  tm = blk >> 2; tn = blk & 3; }
  const int t = threadIdx.x;

  {
    const int r = t >> 4, c4 = t & 15;
    #pragma unroll
    for (int rr = 0; rr < 4; ++rr){
      int row = rr * 16 + r;
      f32x4 v = *(const f32x4*)(src + (long)(tm * 64 + row) * N + tn * 64 + c4 * 4);
      #pragma unroll
      for (int k = 0; k < 4; ++k) sh[row][c4 * 4 + k] = f2bf(v[k]);
    }
  }
  __syncthreads();

  {
    const int n = t >> 2, seg = t & 3;
    bf16x8 o0, o1;
    #pragma unroll
    for (int j = 0; j < 8; ++j){
      o0[j] = (short)sh[seg * 16 + j][n];
      o1[j] = (short)sh[seg * 16 + 8 + j][n];
    }
    unsigned short* dp = dst + (long)(tn * 64 + n) * M + tm * 64 + seg * 16;
    *(bf16x8*)(dp) = o0;
    *(bf16x8*)(dp + 8) = o1;
  }
}

// ---------------- fused depthwise 7x7 conv + bias + LayerNorm -> y bf16
// v4: x rows staged into LDS coalescedly (16 lanes per channel-row, 128B/octet
// contiguous) instead of per-lane 12.5KB-strided reads (64 lines/instr -> 16).
// Staging buffer (256ch x 57f = 57KB) time-shares the LN transpose tile.
__global__ __launch_bounds__(256) void convln_kernel(
    const float* __restrict__ x, const float* __restrict__ cw,
    const float* __restrict__ cb, const float* __restrict__ lng,
    const float* __restrict__ lnb, unsigned short* __restrict__ y){
  __shared__ float buf[256 * 61];   // union: xs[c*57+w] (conv) then tile[c*61+p] (LN)
  __shared__ float part_s[4][64];
  __shared__ float part_q[4][64];
  __shared__ float lg_s[256];
  __shared__ float lb_s[256];

  const int t = threadIdx.x;
  const int blk = blockIdx.x;
  const int b = blk / 56;
  const int h = blk - b * 56;
  const int c = t;

  lg_s[t] = lng[t];
  lb_s[t] = lnb[t];

  float acc[56];
  {
    float bias = cb[c];
    #pragma unroll
    for (int w = 0; w < 56; ++w) acc[w] = bias;
  }

  const int sl = t & 15;          // staging: lane-in-row (0..13 active)
  const int rg = t >> 4;          // staging: row group 0..15
  const float* xb = x + (long)b * 256 * HW;
  const float* cwc = cw + c * 49;

  for (int i = 0; i < 7; ++i){
    int hh = h - 3 + i;
    if (hh >= 0 && hh < 56){                 // uniform per block
      __syncthreads();                       // prior readers of buf done
      if (sl < 14){
        #pragma unroll 4
        for (int k = 0; k < 16; ++k){
          int cr = k * 16 + rg;
          f32x4 v = *(const f32x4*)(xb + (long)cr * HW + hh * 56 + sl * 4);
          *(f32x4*)(buf + cr * 57 + sl * 4) = v;
        }
      }
      __syncthreads();                       // stage complete
      float seg[62];
      seg[0] = seg[1] = seg[2] = 0.f;
      seg[59] = seg[60] = seg[61] = 0.f;
      #pragma unroll
      for (int s4 = 0; s4 < 14; ++s4){
        f32x4 v = *(const f32x4*)(buf + c * 57 + s4 * 4);
        seg[3 + s4 * 4 + 0] = v[0];
        seg[3 + s4 * 4 + 1] = v[1];
        seg[3 + s4 * 4 + 2] = v[2];
        seg[3 + s4 * 4 + 3] = v[3];
      }
      float wt7[7];
      #pragma unroll
      for (int j = 0; j < 7; ++j) wt7[j] = cwc[i * 7 + j];
      #pragma unroll
      for (int j = 0; j < 7; ++j){
        float wj = wt7[j];
        #pragma unroll
        for (int w = 0; w < 56; ++w)
          acc[w] = fmaf(seg[w + j], wj, acc[w]);
      }
    }
  }

  __syncthreads();                 // last seg reads done before tile overwrite
  #pragma unroll
  for (int p = 0; p < 56; ++p) buf[c * 61 + p] = acc[p];
  __syncthreads();

  // per-position sums over c (each wave: uniform c-quarter, lanes = position)
  {
    int p = t & 63; if (p > 55) p = 55;
    const int q = t >> 6;
    float s = 0.f, qq = 0.f;
    #pragma unroll 8
    for (int j = 0; j < 64; ++j){
      float v = buf[(q * 64 + j) * 61 + p];
      s += v; qq = fmaf(v, v, qq);
    }
    part_s[q][p] = s;
    part_q[q][p] = qq;
  }
  __syncthreads();

  // normalize + affine + bf16; 16B slot j stored at (j ^ (pos&7)) — inverse of
  // mlp's swizzled LDS read.
  if (t < 224){
    const int p = t >> 2, c0 = (t & 3) * 64;
    float S = part_s[0][p] + part_s[1][p] + part_s[2][p] + part_s[3][p];
    float Q = part_q[0][p] + part_q[1][p] + part_q[2][p] + part_q[3][p];
    float mu = S * (1.0f / 256.0f);
    float var = Q * (1.0f / 256.0f) - mu * mu;
    float rs = rsqrtf(var + 1e-6f);
    long pos = (long)blk * 56 + p;
    int m7 = (int)(pos & 7);
    unsigned short* yp = y + pos * 256 + c0;
    #pragma unroll
    for (int j = 0; j < 8; ++j){
      bf16x8 o;
      #pragma unroll
      for (int k = 0; k < 8; ++k){
        int cc = c0 + j * 8 + k;
        float v = buf[cc * 61 + p];
        o[k] = (short)f2bf((v - mu) * rs * lg_s[cc] + lb_s[cc]);
      }
      *(bf16x8*)(yp + (j ^ m7) * 8) = o;
    }
  }
}

// ---------------- fused MLP, BM=64, 256 thr
// v4: single-buffer H (8KB, stride 128B, XOR-(m&7) 16B-slot swizzle) ->
// LDS = 40960 B exactly -> 4 blocks/CU (16 waves, was 12). 2 barriers/chunk.
#define LDS_H0 32768
#define MLP_LDS (32768 + 8192)

__global__ __launch_bounds__(256, 4) void mlp_kernel(
    const unsigned short* __restrict__ y, const unsigned short* __restrict__ w1t,
    const unsigned short* __restrict__ w2t, const float* __restrict__ b1,
    const float* __restrict__ b2, float* __restrict__ out){
  __shared__ __align__(16) unsigned char smem[MLP_LDS];
  const int t = threadIdx.x;
  const int wv = t >> 6, lane = t & 63;
  const int lr = lane & 15, lq = lane >> 4;
  const int r7 = lr & 7;
  const int blk = blockIdx.x;
  unsigned char* Hbuf = smem + LDS_H0;

  // stage y tile: 64 rows x 512B, linear (32 groups x 1024B)
  {
    const unsigned char* ybase = (const unsigned char*)(y + (long)blk * 64 * 256);
    #pragma unroll
    for (int r = 0; r < 8; ++r){
      int g = wv * 8 + r;
      load_lds16(ybase + g * 1024 + lane * 16, smem + g * 1024);
    }
  }

  f32x4 acc2[4][4];
  #pragma unroll
  for (int a = 0; a < 4; ++a)
    #pragma unroll
    for (int bb = 0; bb < 4; ++bb) acc2[a][bb] = (f32x4){0.f, 0.f, 0.f, 0.f};

  __syncthreads();   // staging barrier (drains global_load_lds)

  for (int ch = 0; ch < 16; ++ch){
    // preload w1 fragments for this chunk (f = ch*64 + wv*16 + lr), L2-resident
    const unsigned short* w1p = w1t + (((long)ch * 64 + wv * 16 + lr) << 8);
    bf16x8 wf[8];
    #pragma unroll
    for (int ks = 0; ks < 8; ++ks)
      wf[ks] = *(const bf16x8*)(w1p + ks * 32 + lq * 8);

    // phase 1: P^T[f][m] = w1 . y^T
    f32x4 acc1[4];
    #pragma unroll
    for (int mt = 0; mt < 4; ++mt) acc1[mt] = (f32x4){0.f, 0.f, 0.f, 0.f};
    #pragma unroll
    for (int ks = 0; ks < 8; ++ks){
      bf16x8 yf[4];
      #pragma unroll
      for (int mt = 0; mt < 4; ++mt){
        int jl = ks * 4 + lq;
        int ofs = (mt * 16 + lr) * 512 + (((jl & 24) | ((jl ^ r7) & 7)) << 4);
        yf[mt] = *(const bf16x8*)(smem + ofs);
      }
      #pragma unroll
      for (int mt = 0; mt < 4; ++mt)
        acc1[mt] = __builtin_amdgcn_mfma_f32_16x16x32_bf16(wf[ks], yf[mt], acc1[mt], 0, 0, 0);
    }

    // preload w2 fragments (issue before the barrier; latency overlaps it)
    bf16x8 w2f[2][4];
    #pragma unroll
    for (int ks2 = 0; ks2 < 2; ++ks2)
      #pragma unroll
      for (int ct = 0; ct < 4; ++ct)
        w2f[ks2][ct] = *(const bf16x8*)(w2t + (long)(wv * 64 + ct * 16 + lr) * 1024
                                        + ch * 64 + ks2 * 32 + lq * 8);

    // bias + tanh-GELU -> H[m][f_in_chunk], stride 128B, slot ^= (m&7)
    {
      f32x4 bv = *(const f32x4*)(b1 + ch * 64 + wv * 16 + lq * 4);
      const int j = wv * 2 + (lq >> 1);
      const int half = lq & 1;
      #pragma unroll
      for (int mt = 0; mt < 4; ++mt){
        bf16x4 hv;
        #pragma unroll
        for (int r = 0; r < 4; ++r){
          float pv = acc1[mt][r] + bv[r];
          float p2 = pv * pv;
          float u  = pv * fmaf(0.044715f, p2, 1.0f);
          float e  = __builtin_amdgcn_exp2f(-2.3022083f * u);
          float gl = pv * __builtin_amdgcn_rcpf(1.0f + e);
          hv[r] = (short)f2bf(gl);
        }
        int off = (mt * 16 + lr) * 128 + (((j ^ r7)) << 4) + (half << 3);
        *(bf16x4*)(Hbuf + off) = hv;
      }
    }
    __syncthreads();   // H write -> H read

    // phase 2: acc2[c][m] += w2[c][f] . h[m][f]
    #pragma unroll
    for (int ks2 = 0; ks2 < 2; ++ks2){
      bf16x8 hf[4];
      #pragma unroll
      for (int mt = 0; mt < 4; ++mt){
        int off = (mt * 16 + lr) * 128 + (((ks2 * 4 + lq) ^ r7) << 4);
        hf[mt] = *(const bf16x8*)(Hbuf + off);
      }
      #pragma unroll
      for (int ct = 0; ct < 4; ++ct)
        #pragma unroll
        for (int mt = 0; mt < 4; ++mt)
          acc2[ct][mt] = __builtin_amdgcn_mfma_f32_16x16x32_bf16(w2f[ks2][ct], hf[mt], acc2[ct][mt], 0, 0, 0);
    }
    __syncthreads();   // H read -> next chunk's H write
  }

  // epilogue: + b2, NCHW fp32 stores (16 m-consecutive lanes = 64B lines)
  #pragma unroll
  for (int ct = 0; ct < 4; ++ct){
    int cb = wv * 64 + ct * 16 + lq * 4;
    f32x4 b2v = *(const f32x4*)(b2 + cb);
    #pragma unroll
    for (int mt = 0; mt < 4; ++mt){
      int m = mt * 16 + lr;
      unsigned pos = (unsigned)(blk * 64 + m);
      unsigned bimg = pos / 3136u;
      unsigned hw = pos - bimg * 3136u;
      float* op = out + ((long)bimg * 256 + cb) * 3136 + hw;
      #pragma unroll
      for (int r = 0; r < 4; ++r)
        op[r * 3136] = acc2[ct][mt][r] + b2v[r];
    }
  }
}

extern "C" void kernel_launch(void* const* d_in, const int* in_sizes, int n_in,
                              void* d_out, int out_size, void* d_ws, size_t ws_size,
                              hipStream_t stream){
  const float* x  = (const float*)d_in[0];
  const float* cw = (const float*)d_in[1];
  const float* cb = (const float*)d_in[2];
  const float* lg = (const float*)d_in[3];
  const float* lb = (const float*)d_in[4];
  const float* w1 = (const float*)d_in[5];
  const float* b1 = (const float*)d_in[6];
  const float* w2 = (const float*)d_in[7];
  const float* b2 = (const float*)d_in[8];
  float* out = (float*)d_out;

  // workspace: y (51,380,224 B) | w1t (524,288 B) | w2t (524,288 B)
  unsigned short* y   = (unsigned short*)d_ws;
  unsigned short* w1t = (unsigned short*)((char*)d_ws + 51380224);
  unsigned short* w2t = (unsigned short*)((char*)d_ws + 51904512);

  hipLaunchKernelGGL(prep_kernel,   dim3(128),  dim3(256), 0, stream, w1, w2, w1t, w2t);
  hipLaunchKernelGGL(convln_kernel, dim3(1792), dim3(256), 0, stream, x, cw, cb, lg, lb, y);
  hipLaunchKernelGGL(mlp_kernel,    dim3(1568), dim3(256), 0, stream, y, w1t, w2t, b1, b2, out);
}

// Round 4
// 491.398 us; speedup vs baseline: 1.1112x; 1.1112x over previous
//
#include <hip/hip_runtime.h>
#include <math.h>

#define CDIM 256
#define HW 3136
#define HID 1024

typedef __attribute__((ext_vector_type(4))) float f32x4;
typedef __attribute__((ext_vector_type(8))) short bf16x8;
typedef __attribute__((ext_vector_type(4))) short bf16x4;

__device__ __forceinline__ unsigned short f2bf(float f){
  unsigned int u = __float_as_uint(f);
  u += 0x7FFFu + ((u >> 16) & 1u);
  return (unsigned short)(u >> 16);
}

__device__ __forceinline__ void load_lds16(const void* g, void* l){
  __builtin_amdgcn_global_load_lds(
      (const __attribute__((address_space(1))) unsigned int*)g,
      (__attribute__((address_space(3))) unsigned int*)l, 16, 0, 0);
}

// ---------------- prep: w1t[f][c] = w1[c][f]; w2t[c][f] = w2[f][c]  (bf16)
__global__ __launch_bounds__(256) void prep_kernel(
    const float* __restrict__ w1, const float* __restrict__ w2,
    unsigned short* __restrict__ w1t, unsigned short* __restrict__ w2t){
  __shared__ unsigned short sh[64][70];
  int blk = blockIdx.x;
  const float* src; unsigned short* dst; int M, N, tm, tn;
  if (blk < 64){ src = w1; dst = w1t; M = 256;  N = 1024; tm = blk >> 4; tn = blk & 15; }
  else { blk -= 64; src = w2; dst = w2t; M = 1024; N = 256;  tm = blk >> 2; tn = blk & 3; }
  const int t = threadIdx.x;

  {
    const int r = t >> 4, c4 = t & 15;
    #pragma unroll
    for (int rr = 0; rr < 4; ++rr){
      int row = rr * 16 + r;
      f32x4 v = *(const f32x4*)(src + (long)(tm * 64 + row) * N + tn * 64 + c4 * 4);
      #pragma unroll
      for (int k = 0; k < 4; ++k) sh[row][c4 * 4 + k] = f2bf(v[k]);
    }
  }
  __syncthreads();

  {
    const int n = t >> 2, seg = t & 3;
    bf16x8 o0, o1;
    #pragma unroll
    for (int j = 0; j < 8; ++j){
      o0[j] = (short)sh[seg * 16 + j][n];
      o1[j] = (short)sh[seg * 16 + 8 + j][n];
    }
    unsigned short* dp = dst + (long)(tn * 64 + n) * M + tm * 64 + seg * 16;
    *(bf16x8*)(dp) = o0;
    *(bf16x8*)(dp + 8) = o1;
  }
}

// ---------------- fused depthwise 7x7 conv + bias + LayerNorm -> y bf16
// Round-2 body (v4 staging reverted: measured null/negative). New: bijective
// XCD swizzle (1792 = 8*224): XCD k owns images 4k..4k+3 -> x-row reuse stays
// in one XCD's L2. Layout-only; numerics identical.
__global__ __launch_bounds__(256) void convln_kernel(
    const float* __restrict__ x, const float* __restrict__ cw,
    const float* __restrict__ cb, const float* __restrict__ lng,
    const float* __restrict__ lnb, unsigned short* __restrict__ y){
  __shared__ float tile[256 * 61];
  __shared__ float part_s[4][64];
  __shared__ float part_q[4][64];
  __shared__ float lg_s[256];
  __shared__ float lb_s[256];

  const int t = threadIdx.x;
  const int blk0 = blockIdx.x;
  const int blk = (blk0 & 7) * 224 + (blk0 >> 3);   // XCD-contiguous logical id
  const int b = blk / 56;
  const int h = blk - b * 56;
  const int c = t;

  lg_s[t] = lng[t];
  lb_s[t] = lnb[t];

  float acc[56];
  {
    float bias = cb[c];
    #pragma unroll
    for (int w = 0; w < 56; ++w) acc[w] = bias;
  }

  const float* xim = x + (long)(b * 256 + c) * HW;
  const float* cwc = cw + c * 49;
  for (int i = 0; i < 7; ++i){
    int hh = h - 3 + i;
    if (hh >= 0 && hh < 56){                    // uniform per block
      float seg[62];
      seg[0] = seg[1] = seg[2] = 0.f;
      seg[59] = seg[60] = seg[61] = 0.f;
      const float* xrow = xim + hh * 56;
      #pragma unroll
      for (int w4 = 0; w4 < 14; ++w4){
        f32x4 v = *(const f32x4*)(xrow + w4 * 4);
        seg[3 + w4 * 4 + 0] = v[0];
        seg[3 + w4 * 4 + 1] = v[1];
        seg[3 + w4 * 4 + 2] = v[2];
        seg[3 + w4 * 4 + 3] = v[3];
      }
      float wt7[7];
      #pragma unroll
      for (int j = 0; j < 7; ++j) wt7[j] = cwc[i * 7 + j];
      #pragma unroll
      for (int j = 0; j < 7; ++j){
        float wj = wt7[j];
        #pragma unroll
        for (int w = 0; w < 56; ++w)
          acc[w] = fmaf(seg[w + j], wj, acc[w]);
      }
    }
  }

  // write conv result to transpose tile (conflict-free: stride 61)
  #pragma unroll
  for (int p = 0; p < 56; ++p) tile[c * 61 + p] = acc[p];
  __syncthreads();

  // per-position sums over c (each wave: uniform c-quarter, lanes = position)
  {
    int p = t & 63; if (p > 55) p = 55;
    const int q = t >> 6;
    float s = 0.f, qq = 0.f;
    #pragma unroll 8
    for (int j = 0; j < 64; ++j){
      float v = tile[(q * 64 + j) * 61 + p];
      s += v; qq = fmaf(v, v, qq);
    }
    part_s[q][p] = s;
    part_q[q][p] = qq;
  }
  __syncthreads();

  // normalize + affine + bf16; 16B slot j stored at (j ^ (pos&7)) — inverse of
  // mlp's swizzled LDS read.
  if (t < 224){
    const int p = t >> 2, c0 = (t & 3) * 64;
    float S = part_s[0][p] + part_s[1][p] + part_s[2][p] + part_s[3][p];
    float Q = part_q[0][p] + part_q[1][p] + part_q[2][p] + part_q[3][p];
    float mu = S * (1.0f / 256.0f);
    float var = Q * (1.0f / 256.0f) - mu * mu;
    float rs = rsqrtf(var + 1e-6f);
    long pos = (long)blk * 56 + p;
    int m7 = (int)(pos & 7);
    unsigned short* yp = y + pos * 256 + c0;
    #pragma unroll
    for (int j = 0; j < 8; ++j){
      bf16x8 o;
      #pragma unroll
      for (int k = 0; k < 8; ++k){
        int cc = c0 + j * 8 + k;
        float v = tile[cc * 61 + p];
        o[k] = (short)f2bf((v - mu) * rs * lg_s[cc] + lb_s[cc]);
      }
      *(bf16x8*)(yp + (j ^ m7) * 8) = o;
    }
  }
}

// ---------------- fused MLP, BM=64, 256 thr
// v5 = round-2 structure (H dbuf, one sync per chunk, launch_bounds(256,3))
// with the chunk barrier rebuilt as {lgkmcnt(0) asm; sched_barrier; s_barrier}
// — NO vmcnt drain — and weight loads pinned before the memory-clobber asm so
// they stay in flight across the barrier (w2f spans GELU+barrier; wf spans
// barrier+phase2). Correctness: H write->read needs only the DS drain; the
// dbuf WAR hazard is covered by per-wave in-order DS completion + next barrier.
#define LDS_H0 32768
#define MLP_LDS (32768 + 18432)

__global__ __launch_bounds__(256, 3) void mlp_kernel(
    const unsigned short* __restrict__ y, const unsigned short* __restrict__ w1t,
    const unsigned short* __restrict__ w2t, const float* __restrict__ b1,
    const float* __restrict__ b2, float* __restrict__ out){
  __shared__ __align__(16) unsigned char smem[MLP_LDS];
  const int t = threadIdx.x;
  const int wv = t >> 6, lane = t & 63;
  const int lr = lane & 15, lq = lane >> 4;
  const int r7 = lr & 7;
  const int blk = blockIdx.x;

  // stage y tile: 64 rows x 512B, linear (32 groups x 1024B)
  {
    const unsigned char* ybase = (const unsigned char*)(y + (long)blk * 64 * 256);
    #pragma unroll
    for (int r = 0; r < 8; ++r){
      int g = wv * 8 + r;
      load_lds16(ybase + g * 1024 + lane * 16, smem + g * 1024);
    }
  }

  // prologue: wf for chunk 0 (overlaps the staging drain)
  bf16x8 wf[8];
  {
    const unsigned short* w1p = w1t + ((wv * 16 + lr) << 8);
    #pragma unroll
    for (int ks = 0; ks < 8; ++ks)
      wf[ks] = *(const bf16x8*)(w1p + ks * 32 + lq * 8);
  }

  f32x4 acc2[4][4];
  #pragma unroll
  for (int a = 0; a < 4; ++a)
    #pragma unroll
    for (int bb = 0; bb < 4; ++bb) acc2[a][bb] = (f32x4){0.f, 0.f, 0.f, 0.f};

  __syncthreads();   // staging barrier (must drain global_load_lds -> vmcnt)

  for (int ch = 0; ch < 16; ++ch){
    unsigned char* Hbuf = smem + LDS_H0 + (ch & 1) * 9216;

    // phase 1: P^T[f][m] = w1 . y^T  (wf was prefetched last iteration)
    f32x4 acc1[4];
    #pragma unroll
    for (int mt = 0; mt < 4; ++mt) acc1[mt] = (f32x4){0.f, 0.f, 0.f, 0.f};
    #pragma unroll
    for (int ks = 0; ks < 8; ++ks){
      bf16x8 yf[4];
      #pragma unroll
      for (int mt = 0; mt < 4; ++mt){
        int jl = ks * 4 + lq;
        int ofs = (mt * 16 + lr) * 512 + (((jl & 24) | ((jl ^ r7) & 7)) << 4);
        yf[mt] = *(const bf16x8*)(smem + ofs);
      }
      #pragma unroll
      for (int mt = 0; mt < 4; ++mt)
        acc1[mt] = __builtin_amdgcn_mfma_f32_16x16x32_bf16(wf[ks], yf[mt], acc1[mt], 0, 0, 0);
    }

    // issue w2f now: pinned before the "memory" asm below -> in flight across
    // GELU + barrier, consumed in phase 2 with a counted (non-zero) vmcnt.
    bf16x8 w2f[2][4];
    #pragma unroll
    for (int ks2 = 0; ks2 < 2; ++ks2)
      #pragma unroll
      for (int ct = 0; ct < 4; ++ct)
        w2f[ks2][ct] = *(const bf16x8*)(w2t + (long)(wv * 64 + ct * 16 + lr) * 1024
                                        + ch * 64 + ks2 * 32 + lq * 8);

    // bias + tanh-GELU -> H[m][f_in_chunk]
    {
      f32x4 bv = *(const f32x4*)(b1 + ch * 64 + wv * 16 + lq * 4);
      #pragma unroll
      for (int mt = 0; mt < 4; ++mt){
        bf16x4 hv;
        #pragma unroll
        for (int r = 0; r < 4; ++r){
          float pv = acc1[mt][r] + bv[r];
          float p2 = pv * pv;
          float u  = pv * fmaf(0.044715f, p2, 1.0f);
          float e  = __builtin_amdgcn_exp2f(-2.3022083f * u);
          float gl = pv * __builtin_amdgcn_rcpf(1.0f + e);
          hv[r] = (short)f2bf(gl);
        }
        *(bf16x4*)(Hbuf + (mt * 16 + lr) * 144 + wv * 32 + lq * 8) = hv;
      }
    }

    // prefetch wf for next chunk: pinned pre-barrier -> in flight across
    // barrier + phase 2, ready for next phase 1. (wf dead after phase 1.)
    {
      int chn = (ch + 1) & 15;
      const unsigned short* w1p = w1t + (((chn * 64) + wv * 16 + lr) << 8);
      #pragma unroll
      for (int ks = 0; ks < 8; ++ks)
        wf[ks] = *(const bf16x8*)(w1p + ks * 32 + lq * 8);
    }

    // chunk barrier: drain DS only (H writes visible); NO vmcnt drain.
    asm volatile("s_waitcnt lgkmcnt(0)" ::: "memory");
    __builtin_amdgcn_sched_barrier(0);
    __builtin_amdgcn_s_barrier();

    // phase 2: acc2[c][m] += w2[c][f] . h[m][f]
    #pragma unroll
    for (int ks2 = 0; ks2 < 2; ++ks2){
      bf16x8 hf[4];
      #pragma unroll
      for (int mt = 0; mt < 4; ++mt)
        hf[mt] = *(const bf16x8*)(Hbuf + (mt * 16 + lr) * 144 + ks2 * 64 + lq * 16);
      #pragma unroll
      for (int ct = 0; ct < 4; ++ct)
        #pragma unroll
        for (int mt = 0; mt < 4; ++mt)
          acc2[ct][mt] = __builtin_amdgcn_mfma_f32_16x16x32_bf16(w2f[ks2][ct], hf[mt], acc2[ct][mt], 0, 0, 0);
    }
  }

  // epilogue: + b2, NCHW fp32 stores (16 m-consecutive lanes = 64B lines)
  #pragma unroll
  for (int ct = 0; ct < 4; ++ct){
    int cb = wv * 64 + ct * 16 + lq * 4;
    f32x4 b2v = *(const f32x4*)(b2 + cb);
    #pragma unroll
    for (int mt = 0; mt < 4; ++mt){
      int m = mt * 16 + lr;
      unsigned pos = (unsigned)(blk * 64 + m);
      unsigned bimg = pos / 3136u;
      unsigned hw = pos - bimg * 3136u;
      float* op = out + ((long)bimg * 256 + cb) * 3136 + hw;
      #pragma unroll
      for (int r = 0; r < 4; ++r)
        op[r * 3136] = acc2[ct][mt][r] + b2v[r];
    }
  }
}

extern "C" void kernel_launch(void* const* d_in, const int* in_sizes, int n_in,
                              void* d_out, int out_size, void* d_ws, size_t ws_size,
                              hipStream_t stream){
  const float* x  = (const float*)d_in[0];
  const float* cw = (const float*)d_in[1];
  const float* cb = (const float*)d_in[2];
  const float* lg = (const float*)d_in[3];
  const float* lb = (const float*)d_in[4];
  const float* w1 = (const float*)d_in[5];
  const float* b1 = (const float*)d_in[6];
  const float* w2 = (const float*)d_in[7];
  const float* b2 = (const float*)d_in[8];
  float* out = (float*)d_out;

  // workspace: y (51,380,224 B) | w1t (524,288 B) | w2t (524,288 B)
  unsigned short* y   = (unsigned short*)d_ws;
  unsigned short* w1t = (unsigned short*)((char*)d_ws + 51380224);
  unsigned short* w2t = (unsigned short*)((char*)d_ws + 51904512);

  hipLaunchKernelGGL(prep_kernel,   dim3(128),  dim3(256), 0, stream, w1, w2, w1t, w2t);
  hipLaunchKernelGGL(convln_kernel, dim3(1792), dim3(256), 0, stream, x, cw, cb, lg, lb, y);
  hipLaunchKernelGGL(mlp_kernel,    dim3(1568), dim3(256), 0, stream, y, w1t, w2t, b1, b2, out);
}